// Round 1
// 731.424 us; speedup vs baseline: 1.0135x; 1.0135x over previous
//
#include <hip/hip_runtime.h>

#define C_ 256
#define HIN 160
#define NH 23
#define NWIN 529
#define G5 5
#define NGRP 106
#define OPLANE 25600

typedef short bf16x8 __attribute__((ext_vector_type(8)));
typedef float f32x4 __attribute__((ext_vector_type(4)));
typedef unsigned short u16x4 __attribute__((ext_vector_type(4)));

__device__ __forceinline__ unsigned short f2bf(float f) {
    union { float f; unsigned u; } v; v.f = f;
    unsigned r = v.u + 0x7FFFu + ((v.u >> 16) & 1u);
    return (unsigned short)(r >> 16);
}

// ---------------- prep: Wv -> bf16; Wq,Wk -> stacked transposed W2t[c][64] ----------------
__global__ void kprep(const float* __restrict__ Wq, const float* __restrict__ Wk,
                      const float* __restrict__ Wv, unsigned short* __restrict__ WvB,
                      float* __restrict__ W2t) {
    int t = blockIdx.x * 256 + threadIdx.x;
    if (t < 65536) WvB[t] = f2bf(Wv[t]);
    if (t < 16384) {
        int c = t >> 6, ch = t & 63;
        W2t[c * 64 + ch] = (ch < 32) ? Wq[ch * 256 + c] : Wk[(ch - 32) * 256 + c];
    }
}

// ---------------- k12: tiled QK-GEMM (fp32) + S partial accumulation ----------------
#define QST 260   // QKs row stride (floats)
#define XST 264   // Xs row stride (floats)
__launch_bounds__(256, 2)
__global__ void k12(const float* __restrict__ x, const float* __restrict__ W2t,
                    const float* __restrict__ bq, const float* __restrict__ bk,
                    float* __restrict__ Spart) {
    __shared__ float QKs[64 * QST];        // 66560 B
    __shared__ float Xs[8 * XST];          // 8448 B
    __shared__ float Ws[8 * 64];           // 2048 B

    int t = threadIdx.x;
    int g = blockIdx.x;
    int b = g & 7;            // XCD swizzle: one batch per XCD
    int grp = g >> 3;
    int win0 = grp * G5;

    // pixel handled by this thread's staging column
    int wloc = t / 49, p = t % 49;
    int win = win0 + wloc;
    bool pxvalid = (t < 245) && (win < NWIN);
    const float* xp = x;
    if (pxvalid) {
        int wy = win / NH, wx = win % NH;
        int gy = wy * 7 + p / 7, gx = wx * 7 + p % 7;
        int sy = (gy < HIN) ? gy : 158;
        int sx = (gx < HIN) ? gx : 158;
        xp = x + (long)b * C_ * OPLANE + sy * HIN + sx;
    }

    int tx = t & 31, ty = t >> 5;

    float acc[8][8];
#pragma unroll
    for (int i = 0; i < 8; ++i)
#pragma unroll
        for (int j = 0; j < 8; ++j) acc[i][j] = 0.f;

    float prefX[8], prefW[2];
#pragma unroll
    for (int e = 0; e < 8; ++e) prefX[e] = pxvalid ? xp[(long)e * OPLANE] : 0.f;
#pragma unroll
    for (int i = 0; i < 2; ++i) {
        int idx = i * 256 + t, e = idx >> 6, ch = idx & 63;
        prefW[i] = W2t[e * 64 + ch];
    }

    for (int c0 = 0; c0 < 256; c0 += 8) {
#pragma unroll
        for (int e = 0; e < 8; ++e) Xs[e * XST + t] = prefX[e];
#pragma unroll
        for (int i = 0; i < 2; ++i) {
            int idx = i * 256 + t, e = idx >> 6, ch = idx & 63;
            Ws[e * 64 + ch] = prefW[i];
        }
        __syncthreads();
        if (c0 + 8 < 256) {
            int c1 = c0 + 8;
#pragma unroll
            for (int e = 0; e < 8; ++e) prefX[e] = pxvalid ? xp[(long)(c1 + e) * OPLANE] : 0.f;
#pragma unroll
            for (int i = 0; i < 2; ++i) {
                int idx = i * 256 + t, e = idx >> 6, ch = idx & 63;
                prefW[i] = W2t[(c1 + e) * 64 + ch];
            }
        }
#pragma unroll
        for (int kk = 0; kk < 8; ++kk) {
            float wv[8], xv[8];
#pragma unroll
            for (int i = 0; i < 8; ++i) wv[i] = Ws[kk * 64 + ty * 8 + i];
#pragma unroll
            for (int i = 0; i < 8; ++i) xv[i] = Xs[kk * XST + tx * 8 + i];
#pragma unroll
            for (int ci = 0; ci < 8; ++ci)
#pragma unroll
                for (int pi = 0; pi < 8; ++pi)
                    acc[ci][pi] = fmaf(wv[ci], xv[pi], acc[ci][pi]);
        }
        __syncthreads();
    }

    // epilogue: QKs[ch][px] = valid ? acc + bias : 0
    bool cvalid[8];
#pragma unroll
    for (int pi = 0; pi < 8; ++pi) {
        int px = tx * 8 + pi;
        int w = px / 49;
        cvalid[pi] = (px < 245) && (win0 + w < NWIN);
    }
    const float* bb = (ty < 4) ? (bq + ty * 8) : (bk + (ty - 4) * 8);
    float bias[8];
#pragma unroll
    for (int ci = 0; ci < 8; ++ci) bias[ci] = bb[ci];
#pragma unroll
    for (int ci = 0; ci < 8; ++ci) {
        int ch = ty * 8 + ci;
#pragma unroll
        for (int pi = 0; pi < 8; ++pi) {
            int px = tx * 8 + pi;
            QKs[ch * QST + px] = cvalid[pi] ? (acc[ci][pi] + bias[ci]) : 0.f;
        }
    }
    __syncthreads();

    // S partials: S[p][q] += sum_{w,ch} Q[ch,w,p] * K[ch,w,q]
    if (t < 169) {
        int p0 = (t / 13) * 4, q0 = (t % 13) * 4;
        float s[4][4];
#pragma unroll
        for (int r = 0; r < 4; ++r)
#pragma unroll
            for (int cc = 0; cc < 4; ++cc) s[r][cc] = 0.f;
        for (int w = 0; w < G5; ++w) {
            for (int ch = 0; ch < 32; ++ch) {
                const float* qr = &QKs[ch * QST + w * 49 + p0];
                const float* kr = &QKs[(32 + ch) * QST + w * 49 + q0];
                float qv[4] = {qr[0], qr[1], qr[2], qr[3]};
                float kv[4] = {kr[0], kr[1], kr[2], kr[3]};
#pragma unroll
                for (int r = 0; r < 4; ++r)
#pragma unroll
                    for (int cc = 0; cc < 4; ++cc)
                        s[r][cc] = fmaf(qv[r], kv[cc], s[r][cc]);
            }
        }
        float* sp = Spart + (long)(b * NGRP + grp) * 2401;
#pragma unroll
        for (int r = 0; r < 4; ++r) {
            int pp = p0 + r;
            if (pp < 49) {
#pragma unroll
                for (int cc = 0; cc < 4; ++cc) {
                    int qq = q0 + cc;
                    if (qq < 49) sp[pp * 49 + qq] = s[r][cc];
                }
            }
        }
    }
}

// ---------------- kred: parallel reduce of S partials ----------------
__global__ void kred(const float* __restrict__ Spart, float* __restrict__ S) {
    int tg = blockIdx.x * 256 + threadIdx.x;
    if (tg >= 8 * 2401) return;
    int b = tg / 2401, idx = tg % 2401;
    float s = 0.f;
    for (int gr = 0; gr < NGRP; ++gr) s += Spart[(long)(b * NGRP + gr) * 2401 + idx];
    S[b * 2401 + idx] = s;
}

// ---------------- ksoft: row softmax -> zero-padded bf16 attn [8][64][64] ----------------
__global__ void ksoft(const float* __restrict__ S, unsigned short* __restrict__ attnP) {
    int b = blockIdx.x, t = threadIdx.x;
    unsigned short* row = attnP + (b * 64 + t) * 64;
    if (t < 49) {
        const float* sr = S + b * 2401 + t * 49;
        float m = -1e30f;
        for (int j = 0; j < 49; ++j) m = fmaxf(m, sr[j]);
        float den = 0.f;
        for (int j = 0; j < 49; ++j) den += expf(sr[j] - m);
        float inv = 1.f / den;
        for (int j = 0; j < 49; ++j) row[j] = f2bf(expf(sr[j] - m) * inv);
        for (int j = 49; j < 64; ++j) row[j] = 0;
    } else {
        for (int j = 0; j < 64; ++j) row[j] = 0;
    }
}

// ---------------- k3: fused  Y = X·attn^T  (MFMA-1)  then  OUT = Wv·Y + bv  (MFMA-2) ----------------
// Union-LDS version: Xc[256][72] -> Yt[64][264] -> Ot[128][65] all overlay one 36.9 KB buffer
// => 4 blocks/CU (was 3 at 54.3 KB). Single X staging pass. Epilogue transposed through LDS so
// stores are contiguous 49-float runs (window outputs are consecutive in the 161^2-reshaped plane).
#define XCS 72    // Xc row stride (shorts), 144 B: 16B-aligned b128 frag reads
#define YTS 264   // Yt row stride (shorts)
#define OTS 65    // Ot row stride (floats), odd*4B+4 -> spreads banks on frag writes
__launch_bounds__(256, 4)
__global__ void k3(const float* __restrict__ x, const unsigned short* __restrict__ WvB,
                   const unsigned short* __restrict__ attnP, const float* __restrict__ bv,
                   float* __restrict__ out) {
    __shared__ __align__(16) unsigned short U[256 * XCS];   // 36864 B union buffer
    unsigned short* Xc = U;                 // [256][XCS] bf16
    unsigned short* Yt = U;                 // [64][YTS]  bf16 (33792 B)
    float* Ot = (float*)U;                  // [128][OTS] f32  (33280 B)

    int t = threadIdx.x;
    int bw = blockIdx.x;
    int b = bw & 7;           // XCD swizzle: one batch per XCD, adjacent windows adjacent
    int win = bw >> 3;
    int wy = win / NH, wx = win % NH;
    int lane = t & 63;
    int r16 = lane & 15, quad = lane >> 4, q8 = quad * 8;
    int w64 = (t >> 6) * 64;

    const float* xb = x + (long)b * C_ * OPLANE;

    // ---- stage all 64 j-columns once: Xc[c][j] ----
    {
        int j = t & 63;
        bool jvalid = (j < 49);
        int gy = wy * 7 + j / 7, gx = wx * 7 + j % 7;
        int sy = (gy < HIN) ? gy : 158;
        int sx = (gx < HIN) ? gx : 158;
        const float* xs = xb + sy * HIN + sx;
#pragma unroll 4
        for (int c = (t >> 6); c < 256; c += 4) {
            float v = jvalid ? xs[(long)c * OPLANE] : 0.f;
            Xc[c * XCS + j] = f2bf(v);
        }
    }
    __syncthreads();

    f32x4 zero = {0.f, 0.f, 0.f, 0.f};
    f32x4 acc[4][4];
#pragma unroll
    for (int i = 0; i < 4; ++i)
#pragma unroll
        for (int j = 0; j < 4; ++j) acc[i][j] = zero;

    // ---- MFMA-1: D'[c][i] = sum_j X[c][j] * attn[i][j] ----
#pragma unroll
    for (int half = 0; half < 2; ++half) {
        int k0 = half * 32;
        bf16x8 a[4], bfr[4];
#pragma unroll
        for (int mt = 0; mt < 4; ++mt)
            a[mt] = *(const bf16x8*)&Xc[(w64 + mt * 16 + r16) * XCS + k0 + q8];
#pragma unroll
        for (int nt = 0; nt < 4; ++nt)
            bfr[nt] = *(const bf16x8*)&attnP[(b * 64 + nt * 16 + r16) * 64 + k0 + q8];
#pragma unroll
        for (int mt = 0; mt < 4; ++mt)
#pragma unroll
            for (int nt = 0; nt < 4; ++nt)
                acc[mt][nt] = __builtin_amdgcn_mfma_f32_16x16x32_bf16(a[mt], bfr[nt], acc[mt][nt], 0, 0, 0);
    }
    __syncthreads();   // Xc fully consumed into fragments

    // ---- store D' transposed into Yt[i][c] (4 consecutive c per lane -> b64 writes) ----
#pragma unroll
    for (int mt = 0; mt < 4; ++mt) {
        int cb = w64 + mt * 16 + quad * 4;
#pragma unroll
        for (int nt = 0; nt < 4; ++nt) {
            int ic = nt * 16 + r16;
            u16x4 pk;
            pk[0] = f2bf(acc[mt][nt][0]);
            pk[1] = f2bf(acc[mt][nt][1]);
            pk[2] = f2bf(acc[mt][nt][2]);
            pk[3] = f2bf(acc[mt][nt][3]);
            *(u16x4*)&Yt[ic * YTS + cb] = pk;
        }
    }
    __syncthreads();

    // ---- MFMA-2: OUT[ch][i] = sum_c Wv[ch][c] * Y[c][i] (reuse acc registers) ----
#pragma unroll
    for (int i = 0; i < 4; ++i)
#pragma unroll
        for (int j = 0; j < 4; ++j) acc[i][j] = zero;

#pragma unroll
    for (int ks = 0; ks < 8; ++ks) {
        int k0 = ks * 32;
        bf16x8 a[4], bb2[4];
#pragma unroll
        for (int mt = 0; mt < 4; ++mt)
            a[mt] = *(const bf16x8*)&WvB[(w64 + mt * 16 + r16) * 256 + k0 + q8];
#pragma unroll
        for (int nt = 0; nt < 4; ++nt)
            bb2[nt] = *(const bf16x8*)&Yt[(nt * 16 + r16) * YTS + k0 + q8];
#pragma unroll
        for (int mt = 0; mt < 4; ++mt)
#pragma unroll
            for (int nt = 0; nt < 4; ++nt)
                acc[mt][nt] = __builtin_amdgcn_mfma_f32_16x16x32_bf16(a[mt], bb2[nt], acc[mt][nt], 0, 0, 0);
    }
    __syncthreads();   // Yt fully consumed

    // ---- epilogue: transpose through Ot, then coalesced 49-float-run stores ----
    // window's outputs occupy 49 consecutive floats of the 161x161-reshaped plane starting at f0
    float* ob = out + (long)b * C_ * OPLANE;
    int f0 = win * 49;
    int y0 = f0 / 161, x0 = f0 - y0 * 161;
#pragma unroll
    for (int h = 0; h < 2; ++h) {
        if ((w64 >> 7) == h) {   // warps owning channels [h*128, h*128+128)
#pragma unroll
            for (int mt = 0; mt < 4; ++mt) {
                int clb = (w64 & 127) + mt * 16 + quad * 4;
#pragma unroll
                for (int nt = 0; nt < 4; ++nt) {
                    int i = nt * 16 + r16;
                    if (i < 49) {
#pragma unroll
                        for (int r = 0; r < 4; ++r)
                            Ot[(clb + r) * OTS + i] = acc[mt][nt][r];
                    }
                }
            }
        }
        __syncthreads();
        for (int idx = t; idx < 128 * 49; idx += 256) {
            int cl = idx / 49;
            int jj = idx - cl * 49;
            int xx = x0 + jj, yy = y0;
            if (xx >= 161) { ++yy; xx -= 161; }
            if (xx < 160 && yy < 160) {
                int ch = h * 128 + cl;
                ob[ch * OPLANE + yy * 160 + xx] = Ot[cl * OTS + jj] + bv[ch];
            }
        }
        __syncthreads();
    }
}

extern "C" void kernel_launch(void* const* d_in, const int* in_sizes, int n_in,
                              void* d_out, int out_size, void* d_ws, size_t ws_size,
                              hipStream_t stream) {
    const float* x  = (const float*)d_in[0];
    const float* Wq = (const float*)d_in[1];
    const float* bq = (const float*)d_in[2];
    const float* Wk = (const float*)d_in[3];
    const float* bk = (const float*)d_in[4];
    const float* Wv = (const float*)d_in[5];
    const float* bv = (const float*)d_in[6];
    float* out = (float*)d_out;

    char* ws = (char*)d_ws;
    unsigned short* WvB   = (unsigned short*)(ws);                        // 131072 B
    float* W2t            = (float*)(ws + 131072);                        // 65536 B
    float* Spart          = (float*)(ws + 196608);                        // 8144192 B
    float* S              = (float*)(ws + 196608 + 8144192);              // 76832 B
    unsigned short* attnP = (unsigned short*)(ws + 196608 + 8144192 + 76832); // 65536 B

    kprep<<<dim3(256), dim3(256), 0, stream>>>(Wq, Wk, Wv, WvB, W2t);
    k12<<<dim3(8 * NGRP), dim3(256), 0, stream>>>(x, W2t, bq, bk, Spart);
    kred<<<dim3(76), dim3(256), 0, stream>>>(Spart, S);
    ksoft<<<dim3(8), dim3(64), 0, stream>>>(S, attnP);
    k3<<<dim3(8 * NWIN), dim3(256), 0, stream>>>(x, WvB, attnP, bv, out);
}

// Round 2
// 606.112 us; speedup vs baseline: 1.2231x; 1.2067x over previous
//
#include <hip/hip_runtime.h>

#define C_ 256
#define HIN 160
#define NH 23
#define NWIN 529
#define OPLANE 25600

// k12 geometry
#define G3 3
#define NG3 177          // ceil(529/3)
#define NPX 160          // padded px per group (147 used)
#define XSP 40           // Xh/Xl row stride in shorts (80 B, 16B-aligned rows)
#define QST2 164         // QKs row stride (floats)

typedef short bf16x8 __attribute__((ext_vector_type(8)));
typedef float f32x4 __attribute__((ext_vector_type(4)));
typedef unsigned short u16x4 __attribute__((ext_vector_type(4)));

__device__ __forceinline__ unsigned short f2bf(float f) {
    union { float f; unsigned u; } v; v.f = f;
    unsigned r = v.u + 0x7FFFu + ((v.u >> 16) & 1u);
    return (unsigned short)(r >> 16);
}

// ---------------- prep: Wv -> bf16; Wq,Wk -> W2 [64 och][256 c] split bf16 hi/lo; zero S ----------------
__global__ void kprep(const float* __restrict__ Wq, const float* __restrict__ Wk,
                      const float* __restrict__ Wv, unsigned short* __restrict__ WvB,
                      unsigned short* __restrict__ W2h, unsigned short* __restrict__ W2l,
                      float* __restrict__ S) {
    int t = blockIdx.x * 256 + threadIdx.x;
    if (t < 65536) WvB[t] = f2bf(Wv[t]);
    if (t < 16384) {
        int och = t >> 8, c = t & 255;
        float w = (och < 32) ? Wq[och * 256 + c] : Wk[(och - 32) * 256 + c];
        unsigned short h = f2bf(w);
        union { unsigned u; float f; } uh; uh.u = (unsigned)h << 16;
        W2h[t] = h;
        W2l[t] = f2bf(w - uh.f);
    }
    if (t < 8 * 2401) S[t] = 0.f;
}

// ---------------- k12: MFMA split-bf16 QK projection + fp32 S partials -> atomicAdd(S) ----------------
// Per block: 3 windows (147 px, pad 160). M=64 och, N=160 px, K=256 c in 8 chunks of 32.
// Q = Wh*Xh + Wh*Xl + Wl*Xh  (fp32-equivalent); S partials computed from fp32 QKs as before.
__launch_bounds__(256, 2)
__global__ void k12(const float* __restrict__ x, const unsigned short* __restrict__ W2h,
                    const unsigned short* __restrict__ W2l, const float* __restrict__ bq,
                    const float* __restrict__ bk, float* __restrict__ S) {
    __shared__ __align__(16) unsigned short Xh[NPX * XSP];   // 12800 B
    __shared__ __align__(16) unsigned short Xl[NPX * XSP];   // 12800 B
    __shared__ float QKs[64 * QST2];                         // 41984 B  (total 67584 -> 2 blocks/CU)

    int t = threadIdx.x;
    int g = blockIdx.x;
    int b = g & 7, grp = g >> 3;           // XCD swizzle: one batch per XCD
    int win0 = grp * G3;
    const float* xb = x + (long)b * C_ * OPLANE;

    // staging map: thread handles c_loc = (t>>5)+8k (k<4), px = (t&31)+32m (m<5)
    int c8 = t >> 5;
    int j32 = t & 31;
    const float* bases[5];
    bool bval[5];
#pragma unroll
    for (int m = 0; m < 5; ++m) {
        int px = j32 + 32 * m;
        int w = px / 49, p = px - w * 49;
        int win = win0 + w;
        bool v = (px < 147) && (win < NWIN);
        bval[m] = v;
        int wy = win / NH, wx = win - wy * NH;
        int gy = wy * 7 + p / 7, gx = wx * 7 + p % 7;
        int sy = (gy < HIN) ? gy : 158;
        int sx = (gx < HIN) ? gx : 158;
        bases[m] = v ? (xb + sy * HIN + sx) : xb;
    }

    int lane = t & 63, r16 = lane & 15, quad = lane >> 4, q8 = quad * 8;
    int w = t >> 6;   // wave id = m-tile (och rows [16w,16w+16))

    f32x4 zero = {0.f, 0.f, 0.f, 0.f};
    f32x4 acc[10];
#pragma unroll
    for (int nt = 0; nt < 10; ++nt) acc[nt] = zero;

    float pf[20];
#pragma unroll
    for (int k = 0; k < 4; ++k)
#pragma unroll
        for (int m = 0; m < 5; ++m)
            pf[k * 5 + m] = bval[m] ? bases[m][(long)(c8 + 8 * k) * OPLANE] : 0.f;

    for (int c0 = 0; c0 < 256; c0 += 32) {
        // stage current chunk: split fp32 -> bf16 hi/lo
#pragma unroll
        for (int k = 0; k < 4; ++k) {
            int cl = c8 + 8 * k;
#pragma unroll
            for (int m = 0; m < 5; ++m) {
                int px = j32 + 32 * m;
                float v = pf[k * 5 + m];
                unsigned short h = f2bf(v);
                union { unsigned u; float f; } uh; uh.u = (unsigned)h << 16;
                Xh[px * XSP + cl] = h;
                Xl[px * XSP + cl] = f2bf(v - uh.f);
            }
        }
        __syncthreads();
        if (c0 + 32 < 256) {
            int c1 = c0 + 32;
#pragma unroll
            for (int k = 0; k < 4; ++k)
#pragma unroll
                for (int m = 0; m < 5; ++m)
                    pf[k * 5 + m] = bval[m] ? bases[m][(long)(c1 + c8 + 8 * k) * OPLANE] : 0.f;
        }
        bf16x8 ah = *(const bf16x8*)&W2h[(16 * w + r16) * 256 + c0 + q8];
        bf16x8 al = *(const bf16x8*)&W2l[(16 * w + r16) * 256 + c0 + q8];
        __builtin_amdgcn_s_setprio(1);
#pragma unroll
        for (int nt = 0; nt < 10; ++nt) {
            bf16x8 bh = *(const bf16x8*)&Xh[(nt * 16 + r16) * XSP + q8];
            bf16x8 bl = *(const bf16x8*)&Xl[(nt * 16 + r16) * XSP + q8];
            acc[nt] = __builtin_amdgcn_mfma_f32_16x16x32_bf16(ah, bh, acc[nt], 0, 0, 0);
            acc[nt] = __builtin_amdgcn_mfma_f32_16x16x32_bf16(ah, bl, acc[nt], 0, 0, 0);
            acc[nt] = __builtin_amdgcn_mfma_f32_16x16x32_bf16(al, bh, acc[nt], 0, 0, 0);
        }
        __builtin_amdgcn_s_setprio(0);
        __syncthreads();
    }

    // epilogue: QKs[och][px] = valid ? acc + bias : 0
    float bias[4];
#pragma unroll
    for (int r = 0; r < 4; ++r) {
        int och = 16 * w + quad * 4 + r;
        bias[r] = (och < 32) ? bq[och] : bk[och - 32];
    }
#pragma unroll
    for (int nt = 0; nt < 10; ++nt) {
        int px = nt * 16 + r16;
        int wof = px / 49;
        bool v = (px < 147) && (win0 + wof < NWIN);
#pragma unroll
        for (int r = 0; r < 4; ++r) {
            int och = 16 * w + quad * 4 + r;
            QKs[och * QST2 + px] = v ? (acc[nt][r] + bias[r]) : 0.f;
        }
    }
    __syncthreads();

    // S partials: S[p][q] += sum_{w,ch} Q[ch,w,p] * K[ch,w,q]  (fp32, then device atomics)
    if (t < 169) {
        int p0 = (t / 13) * 4, q0 = (t % 13) * 4;
        float s[4][4];
#pragma unroll
        for (int r = 0; r < 4; ++r)
#pragma unroll
            for (int cc = 0; cc < 4; ++cc) s[r][cc] = 0.f;
        for (int wi = 0; wi < G3; ++wi) {
            for (int ch = 0; ch < 32; ++ch) {
                const float* qr = &QKs[ch * QST2 + wi * 49 + p0];
                const float* kr = &QKs[(32 + ch) * QST2 + wi * 49 + q0];
                float qv[4] = {qr[0], qr[1], qr[2], qr[3]};
                float kv[4] = {kr[0], kr[1], kr[2], kr[3]};
#pragma unroll
                for (int r = 0; r < 4; ++r)
#pragma unroll
                    for (int cc = 0; cc < 4; ++cc)
                        s[r][cc] = fmaf(qv[r], kv[cc], s[r][cc]);
            }
        }
        float* sp = S + b * 2401;
#pragma unroll
        for (int r = 0; r < 4; ++r) {
            int pp = p0 + r;
            if (pp < 49) {
#pragma unroll
                for (int cc = 0; cc < 4; ++cc) {
                    int qq = q0 + cc;
                    if (qq < 49) atomicAdd(&sp[pp * 49 + qq], s[r][cc]);
                }
            }
        }
    }
}

// ---------------- ksoft: row softmax -> zero-padded bf16 attn [8][64][64] ----------------
__global__ void ksoft(const float* __restrict__ S, unsigned short* __restrict__ attnP) {
    int b = blockIdx.x, t = threadIdx.x;
    unsigned short* row = attnP + (b * 64 + t) * 64;
    if (t < 49) {
        const float* sr = S + b * 2401 + t * 49;
        float m = -1e30f;
        for (int j = 0; j < 49; ++j) m = fmaxf(m, sr[j]);
        float den = 0.f;
        for (int j = 0; j < 49; ++j) den += expf(sr[j] - m);
        float inv = 1.f / den;
        for (int j = 0; j < 49; ++j) row[j] = f2bf(expf(sr[j] - m) * inv);
        for (int j = 49; j < 64; ++j) row[j] = 0;
    } else {
        for (int j = 0; j < 64; ++j) row[j] = 0;
    }
}

// ---------------- k3: fused  Y = X·attn^T  (MFMA-1)  then  OUT = Wv·Y + bv  (MFMA-2) ----------------
// Union-LDS 36.9 KB (4 blocks/CU). Staging ILP=16. 4 barriers total. Warp-private epilogue strips
// (each warp's acc2 covers only its own 64-channel band -> no inter-warp sync after Yt-consumed bar).
#define XCS 72    // Xc row stride (shorts), 144 B
#define YTS 264   // Yt row stride (shorts)
#define OTS2 50   // Os strip row stride (floats)
__launch_bounds__(256, 4)
__global__ void k3(const float* __restrict__ x, const unsigned short* __restrict__ WvB,
                   const unsigned short* __restrict__ attnP, const float* __restrict__ bv,
                   float* __restrict__ out) {
    __shared__ __align__(16) unsigned short U[256 * XCS];   // 36864 B union buffer
    unsigned short* Xc = U;                 // [256][XCS] bf16
    unsigned short* Yt = U;                 // [64][YTS]  bf16 (33792 B)

    int t = threadIdx.x;
    int bw = blockIdx.x;
    int b = bw & 7;           // XCD swizzle
    int win = bw >> 3;
    int wy = win / NH, wx = win % NH;
    int lane = t & 63;
    int r16 = lane & 15, quad = lane >> 4, q8 = quad * 8;
    int w64 = (t >> 6) * 64;

    const float* xb = x + (long)b * C_ * OPLANE;

    // ---- stage all 64 j-columns once, 16-deep load batches ----
    {
        int j = t & 63;
        bool jvalid = (j < 49);
        int gy = wy * 7 + j / 7, gx = wx * 7 + j % 7;
        int sy = (gy < HIN) ? gy : 158;
        int sx = (gx < HIN) ? gx : 158;
        const float* xs = xb + sy * HIN + sx;
        int cb = t >> 6;
#pragma unroll
        for (int gg = 0; gg < 4; ++gg) {
            float v[16];
#pragma unroll
            for (int i = 0; i < 16; ++i)
                v[i] = jvalid ? xs[(long)(cb + 4 * (gg * 16 + i)) * OPLANE] : 0.f;
#pragma unroll
            for (int i = 0; i < 16; ++i)
                Xc[(cb + 4 * (gg * 16 + i)) * XCS + j] = f2bf(v[i]);
        }
    }
    __syncthreads();

    f32x4 zero = {0.f, 0.f, 0.f, 0.f};
    f32x4 acc[4][4];
#pragma unroll
    for (int i = 0; i < 4; ++i)
#pragma unroll
        for (int j = 0; j < 4; ++j) acc[i][j] = zero;

    // ---- MFMA-1: D'[c][i] = sum_j X[c][j] * attn[i][j] ----
    __builtin_amdgcn_s_setprio(1);
#pragma unroll
    for (int half = 0; half < 2; ++half) {
        int k0 = half * 32;
        bf16x8 a[4], bfr[4];
#pragma unroll
        for (int mt = 0; mt < 4; ++mt)
            a[mt] = *(const bf16x8*)&Xc[(w64 + mt * 16 + r16) * XCS + k0 + q8];
#pragma unroll
        for (int nt = 0; nt < 4; ++nt)
            bfr[nt] = *(const bf16x8*)&attnP[(b * 64 + nt * 16 + r16) * 64 + k0 + q8];
#pragma unroll
        for (int mt = 0; mt < 4; ++mt)
#pragma unroll
            for (int nt = 0; nt < 4; ++nt)
                acc[mt][nt] = __builtin_amdgcn_mfma_f32_16x16x32_bf16(a[mt], bfr[nt], acc[mt][nt], 0, 0, 0);
    }
    __builtin_amdgcn_s_setprio(0);
    __syncthreads();   // Xc fully consumed

    // ---- store D' transposed into Yt[i][c] ----
#pragma unroll
    for (int mt = 0; mt < 4; ++mt) {
        int cb = w64 + mt * 16 + quad * 4;
#pragma unroll
        for (int nt = 0; nt < 4; ++nt) {
            int ic = nt * 16 + r16;
            u16x4 pk;
            pk[0] = f2bf(acc[mt][nt][0]);
            pk[1] = f2bf(acc[mt][nt][1]);
            pk[2] = f2bf(acc[mt][nt][2]);
            pk[3] = f2bf(acc[mt][nt][3]);
            *(u16x4*)&Yt[ic * YTS + cb] = pk;
        }
    }
    __syncthreads();

    // ---- MFMA-2: OUT[ch][i] = sum_c Wv[ch][c] * Y[c][i] ----
#pragma unroll
    for (int i = 0; i < 4; ++i)
#pragma unroll
        for (int j = 0; j < 4; ++j) acc[i][j] = zero;

    __builtin_amdgcn_s_setprio(1);
#pragma unroll
    for (int ks = 0; ks < 8; ++ks) {
        int k0 = ks * 32;
        bf16x8 a[4], bb2[4];
#pragma unroll
        for (int mt = 0; mt < 4; ++mt)
            a[mt] = *(const bf16x8*)&WvB[(w64 + mt * 16 + r16) * 256 + k0 + q8];
#pragma unroll
        for (int nt = 0; nt < 4; ++nt)
            bb2[nt] = *(const bf16x8*)&Yt[(nt * 16 + r16) * YTS + k0 + q8];
#pragma unroll
        for (int mt = 0; mt < 4; ++mt)
#pragma unroll
            for (int nt = 0; nt < 4; ++nt)
                acc[mt][nt] = __builtin_amdgcn_mfma_f32_16x16x32_bf16(a[mt], bb2[nt], acc[mt][nt], 0, 0, 0);
    }
    __builtin_amdgcn_s_setprio(0);
    __syncthreads();   // Yt fully consumed -> strips may overlay

    // ---- epilogue: warp-private transpose strips, coalesced 49-float-run stores, no more barriers ----
    float* Os = (float*)U + (t >> 6) * (32 * OTS2);   // 6400 B per warp, 25600 B total
    float* ob = out + (long)b * C_ * OPLANE;
    int f0 = win * 49;
    int y0 = f0 / 161, x0 = f0 - y0 * 161;
#pragma unroll
    for (int sub = 0; sub < 2; ++sub) {
#pragma unroll
        for (int mt2 = 0; mt2 < 2; ++mt2) {
            int mt = sub * 2 + mt2;
            int clb = mt2 * 16 + quad * 4;
            int chb = w64 + mt * 16 + quad * 4;
            float bvl[4];
#pragma unroll
            for (int r = 0; r < 4; ++r) bvl[r] = bv[chb + r];
#pragma unroll
            for (int nt = 0; nt < 4; ++nt) {
                int i = nt * 16 + r16;
                if (i < 49) {
#pragma unroll
                    for (int r = 0; r < 4; ++r)
                        Os[(clb + r) * OTS2 + i] = acc[mt][nt][r] + bvl[r];
                }
            }
        }
        // same-warp read & store (in-order DS per wave: no barrier needed)
        for (int idx = lane; idx < 32 * 49; idx += 64) {
            int cl = idx / 49, jj = idx - cl * 49;
            int xx = x0 + jj, yy = y0;
            if (xx >= 161) { ++yy; xx -= 161; }
            if (xx < 160 && yy < 160) {
                int ch = w64 + sub * 32 + cl;
                ob[ch * OPLANE + yy * 160 + xx] = Os[cl * OTS2 + jj];
            }
        }
    }
}

extern "C" void kernel_launch(void* const* d_in, const int* in_sizes, int n_in,
                              void* d_out, int out_size, void* d_ws, size_t ws_size,
                              hipStream_t stream) {
    const float* x  = (const float*)d_in[0];
    const float* Wq = (const float*)d_in[1];
    const float* bq = (const float*)d_in[2];
    const float* Wk = (const float*)d_in[3];
    const float* bk = (const float*)d_in[4];
    const float* Wv = (const float*)d_in[5];
    const float* bv = (const float*)d_in[6];
    float* out = (float*)d_out;

    char* ws = (char*)d_ws;
    unsigned short* WvB   = (unsigned short*)(ws);             // 131072 B
    unsigned short* W2h   = (unsigned short*)(ws + 131072);    // 32768 B
    unsigned short* W2l   = (unsigned short*)(ws + 163840);    // 32768 B
    float* S              = (float*)(ws + 196608);             // 76832 B
    unsigned short* attnP = (unsigned short*)(ws + 273440);    // 65536 B

    kprep<<<dim3(256), dim3(256), 0, stream>>>(Wq, Wk, Wv, WvB, W2h, W2l, S);
    k12<<<dim3(8 * NG3), dim3(256), 0, stream>>>(x, W2h, W2l, bq, bk, S);
    ksoft<<<dim3(8), dim3(64), 0, stream>>>(S, attnP);
    k3<<<dim3(8 * NWIN), dim3(256), 0, stream>>>(x, WvB, attnP, bv, out);
}